// Round 4
// baseline (717.359 us; speedup 1.0000x reference)
//
#include <hip/hip_runtime.h>

// VQ-VAE forward, MI355X round 4: NHWC + MFMA implicit GEMM for the 4 big
// layers; LDS-staged VALU kernels for conv1 / convt3 / VQ. fp32 I/O,
// bf16 intermediates.

typedef __attribute__((ext_vector_type(8))) short     short8;
typedef __attribute__((ext_vector_type(8))) __bf16    bf16x8;
typedef __attribute__((ext_vector_type(4))) float     f32x4;

#define BATCH 32

__device__ __forceinline__ float b2f(unsigned short b) {
  union { unsigned u; float f; } v; v.u = ((unsigned)b) << 16; return v.f;
}
__device__ __forceinline__ unsigned short f2b(float f) {  // round-to-nearest-even
  union { float f; unsigned u; } v; v.f = f;
  unsigned r = v.u + 0x7FFF + ((v.u >> 16) & 1);
  return (unsigned short)(r >> 16);
}

// ---------------- weight prep: reorganize to [tap][co][ci] bf16 -------------
__global__ __launch_bounds__(256) void prep2_k(const float* __restrict__ w,
                                               unsigned short* __restrict__ wq) {
  const int i = blockIdx.x*256 + threadIdx.x;                 // 131072 exact
  const int ci = i & 63, co = (i >> 6) & 127, t = i >> 13;
  wq[i] = f2b(w[(co*64 + ci)*16 + t]);                        // ew2 OIHW(128,64,4,4)
}
__global__ __launch_bounds__(256) void prep3_k(const float* __restrict__ w,
                                               unsigned short* __restrict__ wq) {
  const int i = blockIdx.x*256 + threadIdx.x;                 // 36864 exact
  const int ci = i & 127, co = (i >> 7) & 31, t = i >> 12;
  wq[i] = f2b(w[(co*128 + ci)*9 + t]);                        // ew3 OIHW(32,128,3,3)
}
__global__ __launch_bounds__(256) void prep4_k(const float* __restrict__ w,
                                               unsigned short* __restrict__ wq) {
  const int i = blockIdx.x*256 + threadIdx.x;                 // 36864 exact
  const int ci = i & 31, co = (i >> 5) & 127, t = i >> 12;
  wq[i] = f2b(w[(ci*128 + co)*9 + (8 - t)]);                  // dw1(32,128,3,3), flipped
}
__global__ __launch_bounds__(256) void prep5_k(const float* __restrict__ w,
                                               unsigned short* __restrict__ wq) {
  const int i = blockIdx.x*256 + threadIdx.x;                 // 131072 exact
  const int ci = i & 127, co = (i >> 7) & 63, t = (i >> 13) & 3, p = i >> 15;
  const int ky = 2 - 2*(t >> 1) + (1 - (p >> 1));
  const int kx = 2 - 2*(t & 1)  + (1 - (p & 1));
  wq[i] = f2b(w[(ci*64 + co)*16 + ky*4 + kx]);                // dw2(128,64,4,4)
}

// --------- MFMA implicit-GEMM conv: NHWC in -> NHWC out (64x64 spatial) -----
// M = 32*64*64 = 131072 output positions, block tile 128M x COUT, 4 waves.
// A (im2col) and B (weights [tap][co][ci]) staged per (tap, 32-ci chunk).
template<int CIN,int COUT,int HIN,int S,int KW,int NTAPS,int OSTRIDE,int P,
         bool PARITY,bool RELU,bool INF32,bool OUTF32>
__global__ __launch_bounds__(256) void mconv_k(const void* __restrict__ in_,
    const unsigned short* __restrict__ wq_, const float* __restrict__ bias,
    void* __restrict__ out_) {
  constexpr int NF  = COUT / 16;
  constexpr int NCH = CIN / 32;
  __shared__ short Al[128*40];      // 128 rows x 32 k, stride 40 (80B, 16B-mult)
  __shared__ short Bl[COUT*40];
  int py = 0, px = 0, PY = P, PX = P;
  const unsigned short* wq = wq_;
  if (PARITY) {
    py = blockIdx.y >> 1; px = blockIdx.y & 1;
    PY = 1 - py; PX = 1 - px;
    wq += blockIdx.y * (NTAPS*COUT*CIN);
  }
  const int m0 = blockIdx.x * 128;
  const int w  = threadIdx.x >> 6, l = threadIdx.x & 63;
  const int lm = l & 15, lk = l >> 4;
  f32x4 acc[2][NF];
  #pragma unroll
  for (int mi = 0; mi < 2; ++mi)
    #pragma unroll
    for (int ni = 0; ni < NF; ++ni) acc[mi][ni] = (f32x4)0.0f;

  for (int tap = 0; tap < NTAPS; ++tap) {
    const int ky = tap / KW, kx = tap % KW;
    for (int ch = 0; ch < NCH; ++ch) {
      const int c0 = ch * 32;
      __syncthreads();                       // prev iter frag reads done
      // ---- A stage: 128 rows x 64B, 4 lanes/row ----
      for (int s = threadIdx.x; s < 512; s += 256) {
        const int row = s >> 2, part = s & 3;
        const int m = m0 + row;
        const int n = m >> 12, oy = (m >> 6) & 63, ox = m & 63;
        const int iy = oy*S - PY + ky, ix = ox*S - PX + kx;
        short8 v = (short8)(short)0;
        if (iy >= 0 && iy < HIN && ix >= 0 && ix < HIN) {
          const int base = ((n*HIN + iy)*HIN + ix)*CIN + c0 + part*8;
          if (INF32) {
            const float* pf = (const float*)in_ + base;
            const f32x4 f0 = *(const f32x4*)pf;
            const f32x4 f1 = *(const f32x4*)(pf + 4);
            #pragma unroll
            for (int j = 0; j < 4; ++j) {
              v[j]     = (short)f2b(f0[j]);
              v[j + 4] = (short)f2b(f1[j]);
            }
          } else {
            v = *(const short8*)((const unsigned short*)in_ + base);
          }
        }
        *(short8*)&Al[row*40 + part*8] = v;
      }
      // ---- B stage: COUT rows x 64B ----
      for (int s = threadIdx.x; s < COUT*4; s += 256) {
        const int co = s >> 2, part = s & 3;
        *(short8*)&Bl[co*40 + part*8] =
            *(const short8*)(wq + (tap*COUT + co)*CIN + c0 + part*8);
      }
      __syncthreads();
      // ---- fragments + MFMA ----
      short8 av[2];
      #pragma unroll
      for (int mi = 0; mi < 2; ++mi)
        av[mi] = *(const short8*)&Al[(w*32 + mi*16 + lm)*40 + lk*8];
      #pragma unroll
      for (int ni = 0; ni < NF; ++ni) {
        const short8 bv = *(const short8*)&Bl[(ni*16 + lm)*40 + lk*8];
        #pragma unroll
        for (int mi = 0; mi < 2; ++mi)
          acc[mi][ni] = __builtin_amdgcn_mfma_f32_16x16x32_bf16(
              __builtin_bit_cast(bf16x8, av[mi]),
              __builtin_bit_cast(bf16x8, bv),
              acc[mi][ni], 0, 0, 0);
      }
    }
  }
  // ---- epilogue: C/D layout col=lane&15 (n), row=(lane>>4)*4+reg (m) ----
  #pragma unroll
  for (int ni = 0; ni < NF; ++ni) {
    const int co = ni*16 + lm;
    const float bv = bias[co];
    #pragma unroll
    for (int mi = 0; mi < 2; ++mi) {
      #pragma unroll
      for (int r = 0; r < 4; ++r) {
        const int ml = w*32 + mi*16 + lk*4 + r;
        const int m  = m0 + ml;
        float vv = acc[mi][ni][r] + bv;
        if (RELU) vv = fmaxf(vv, 0.f);
        int off;
        if (OSTRIDE == 1) {
          off = m*COUT + co;
        } else {
          const int n = m >> 12, oy = (m >> 6) & 63, ox = m & 63;
          off = ((n*128 + oy*2 + py)*128 + ox*2 + px)*COUT + co;
        }
        if (OUTF32) ((float*)out_)[off] = vv;
        else ((unsigned short*)out_)[off] = f2b(vv);
      }
    }
  }
}

// -------- conv1: x NCHW fp32 (3ch) -> h1 NHWC bf16 [32,128,128,64] ----------
// block = (n, 4-output-row group). LDS-staged 10 input rows x 3 ch.
__global__ __launch_bounds__(256) void conv1_k(const float* __restrict__ x,
    const float* __restrict__ w, const float* __restrict__ bias,
    unsigned short* __restrict__ out) {
  __shared__ float XL[3*10*256];   // [ci][r][x], iy = 8q-1+r  (30 KB)
  __shared__ float wl[64*48];      // OIHW flat (12 KB)
  __shared__ float bl[64];
  const int n = blockIdx.x >> 5, q = blockIdx.x & 31;
  for (int i = threadIdx.x; i < 3072; i += 256) wl[i] = w[i];
  if (threadIdx.x < 64) bl[threadIdx.x] = bias[threadIdx.x];
  for (int i = threadIdx.x; i < 7680; i += 256) {
    const int ci = i / 2560, rem = i % 2560, r = rem >> 8, xc = rem & 255;
    const int iy = 8*q - 1 + r;
    XL[i] = (iy >= 0 && iy < 256) ? x[((n*3 + ci)*256 + iy)*256 + xc] : 0.f;
  }
  __syncthreads();
  float xin[2][48];
  int oyl[2], oxl[2];
  #pragma unroll
  for (int s = 0; s < 2; ++s) {
    const int pos = threadIdx.x + 256*s;
    const int oy = pos >> 7, ox = pos & 127;
    oyl[s] = oy; oxl[s] = ox;
    #pragma unroll
    for (int ci = 0; ci < 3; ++ci)
      #pragma unroll
      for (int ky = 0; ky < 4; ++ky) {
        const int r = 2*oy + ky;
        #pragma unroll
        for (int kx = 0; kx < 4; ++kx) {
          const int ix = 2*ox - 1 + kx;
          xin[s][ci*16 + ky*4 + kx] =
              (ix >= 0 && ix < 256) ? XL[ci*2560 + r*256 + ix] : 0.f;
        }
      }
  }
  const long ob0 = ((long)((n*128 + q*4 + oyl[0])*128 + oxl[0]))*64;
  const long ob1 = ((long)((n*128 + q*4 + oyl[1])*128 + oxl[1]))*64;
  #pragma unroll
  for (int cb = 0; cb < 8; ++cb) {
    short8 sv0, sv1;
    #pragma unroll
    for (int j = 0; j < 8; ++j) {
      const int co = cb*8 + j;
      float a0 = bl[co], a1 = a0;
      #pragma unroll
      for (int qd = 0; qd < 12; ++qd) {
        const f32x4 wv = *(const f32x4*)&wl[co*48 + qd*4];
        #pragma unroll
        for (int e = 0; e < 4; ++e) {
          a0 = fmaf(xin[0][qd*4 + e], wv[e], a0);
          a1 = fmaf(xin[1][qd*4 + e], wv[e], a1);
        }
      }
      sv0[j] = (short)f2b(fmaxf(a0, 0.f));
      sv1[j] = (short)f2b(fmaxf(a1, 0.f));
    }
    *(short8*)&out[ob0 + cb*8] = sv0;
    *(short8*)&out[ob1 + cb*8] = sv1;
  }
}

// ------- VQ: z fp32 [131072,32] -> zq fp32 [131072,32] + loss partials ------
// embed chunk transposed [c][j] in LDS; 4-code vector dot accumulation.
__global__ __launch_bounds__(256) void vq_k(const float* __restrict__ z,
    const float* __restrict__ embed, float* __restrict__ zq,
    float* __restrict__ partial) {
  __shared__ float EL[32*256];    // [c][j] transposed chunk (32 KB)
  __shared__ float en[256];
  __shared__ float red[256];
  const int p = blockIdx.x*256 + threadIdx.x;   // 0..131071
  float zf[32];
  #pragma unroll
  for (int c4 = 0; c4 < 8; ++c4) {
    const f32x4 v = *(const f32x4*)&z[(long)p*32 + c4*4];
    #pragma unroll
    for (int e = 0; e < 4; ++e) zf[c4*4 + e] = v[e];
  }
  float best = 1e30f; int bi = 0;
  for (int chunk = 0; chunk < 2; ++chunk) {
    __syncthreads();
    for (int i = threadIdx.x; i < 8192; i += 256) {
      const int c = i >> 8, j = i & 255;
      EL[c*256 + j] = embed[(chunk*256 + j)*32 + c];
    }
    __syncthreads();
    {
      float s = 0.f;
      #pragma unroll
      for (int c = 0; c < 32; ++c)
        s = fmaf(EL[c*256 + threadIdx.x], EL[c*256 + threadIdx.x], s);
      en[threadIdx.x] = s;
    }
    __syncthreads();
    for (int j8 = 0; j8 < 256; j8 += 8) {
      f32x4 dA = (f32x4)0.0f, dB = (f32x4)0.0f;
      #pragma unroll
      for (int c = 0; c < 32; ++c) {
        const f32x4 eA = *(const f32x4*)&EL[c*256 + j8];
        const f32x4 eB = *(const f32x4*)&EL[c*256 + j8 + 4];
        dA += eA * zf[c];
        dB += eB * zf[c];
      }
      #pragma unroll
      for (int k = 0; k < 4; ++k) {
        const float d = en[j8 + k] - 2.f*dA[k];
        if (d < best) { best = d; bi = chunk*256 + j8 + k; }
      }
      #pragma unroll
      for (int k = 0; k < 4; ++k) {
        const float d = en[j8 + 4 + k] - 2.f*dB[k];
        if (d < best) { best = d; bi = chunk*256 + j8 + 4 + k; }
      }
    }
  }
  float se = 0.f;
  #pragma unroll
  for (int c = 0; c < 32; ++c) {
    const float e = embed[bi*32 + c];          // exact fp32 codeword
    zq[(long)p*32 + c] = e;
    const float df = e - zf[c];
    se = fmaf(df, df, se);
  }
  red[threadIdx.x] = se; __syncthreads();
  for (int s = 128; s > 0; s >>= 1) {
    if (threadIdx.x < s) red[threadIdx.x] += red[threadIdx.x + s];
    __syncthreads();
  }
  if (threadIdx.x == 0) partial[blockIdx.x] = red[0];
}

__global__ __launch_bounds__(512) void loss_k(const float* __restrict__ part,
                                              float* __restrict__ out) {
  __shared__ float red[512];
  const int t = threadIdx.x;
  red[t] = part[t]; __syncthreads();
  for (int s = 256; s > 0; s >>= 1) {
    if (t < s) red[t] += red[t + s];
    __syncthreads();
  }
  if (t == 0) out[0] = red[0] * (1.25f / (131072.f * 32.f));
}

// -------- convt3: d2 NHWC bf16 [32,128,128,64] -> x_recon NCHW fp32 ---------
// block = (n, input-row q): computes output rows 2q, 2q+1 (both parities).
// LDS-staged 3 input rows + weights [tap][co][ci]. px is wave-uniform.
__global__ __launch_bounds__(256) void convt3_k(const unsigned short* __restrict__ in,
    const float* __restrict__ w, const float* __restrict__ bias,
    float* __restrict__ out) {
  __shared__ short IL[3*128*64];     // [r][ix][ci], iy = q-1+r  (48 KB)
  __shared__ float wt[16*192];       // [tap][co][ci]            (12 KB)
  const int n = blockIdx.x >> 7, q = blockIdx.x & 127;
  for (int i = threadIdx.x; i < 3072; i += 256) {
    const int tap = i / 192, rem = i % 192, co = rem >> 6, ci = rem & 63;
    wt[i] = w[(ci*3 + co)*16 + tap];                // dw3 (64,3,4,4)
  }
  for (int i = threadIdx.x; i < 3072; i += 256) {   // 3*128*8 short8 chunks
    const int r = i >> 10, rem = i & 1023, ix = rem >> 3, part = rem & 7;
    const int iy = q - 1 + r;
    short8 v = (short8)(short)0;
    if (iy >= 0 && iy < 128)
      v = *(const short8*)(in + (((long)(n*128 + iy)*128 + ix)*64 + part*8));
    *(short8*)&IL[(r*128 + ix)*64 + part*8] = v;
  }
  __syncthreads();
  const int px = threadIdx.x >> 7, xq = threadIdx.x & 127;  // px wave-uniform
  float acc[2][3];
  #pragma unroll
  for (int py = 0; py < 2; ++py)
    #pragma unroll
    for (int co = 0; co < 3; ++co) acc[py][co] = bias[co];
  #pragma unroll
  for (int py = 0; py < 2; ++py)
    #pragma unroll
    for (int a = 0; a < 2; ++a) {
      const int r = py + a;                  // iy = q-1+py+a (zero-padded rows)
      const int ky = 2 - 2*a + (1 - py);
      #pragma unroll
      for (int b = 0; b < 2; ++b) {
        const int ix = xq - 1 + px + b;
        if (ix < 0 || ix >= 128) continue;
        const int kx = 2 - 2*b + (1 - px);
        const int tap = ky*4 + kx;
        const short* ip = &IL[(r*128 + ix)*64];
        #pragma unroll
        for (int c8 = 0; c8 < 8; ++c8) {
          const short8 v8 = *(const short8*)(ip + c8*8);
          float vf[8];
          #pragma unroll
          for (int j = 0; j < 8; ++j) vf[j] = b2f((unsigned short)v8[j]);
          #pragma unroll
          for (int co = 0; co < 3; ++co) {
            const f32x4 w0 = *(const f32x4*)&wt[tap*192 + co*64 + c8*8];
            const f32x4 w1 = *(const f32x4*)&wt[tap*192 + co*64 + c8*8 + 4];
            float a0 = acc[py][co];
            a0 = fmaf(vf[0], w0[0], a0);
            a0 = fmaf(vf[1], w0[1], a0);
            a0 = fmaf(vf[2], w0[2], a0);
            a0 = fmaf(vf[3], w0[3], a0);
            a0 = fmaf(vf[4], w1[0], a0);
            a0 = fmaf(vf[5], w1[1], a0);
            a0 = fmaf(vf[6], w1[2], a0);
            a0 = fmaf(vf[7], w1[3], a0);
            acc[py][co] = a0;
          }
        }
      }
    }
  const int ox = xq*2 + px;
  #pragma unroll
  for (int py = 0; py < 2; ++py) {
    const int sp = (2*q + py)*256 + ox;
    #pragma unroll
    for (int co = 0; co < 3; ++co)
      out[((long)(n*3 + co))*65536 + sp] = acc[py][co];
  }
}

extern "C" void kernel_launch(void* const* d_in, const int* in_sizes, int n_in,
                              void* d_out, int out_size, void* d_ws, size_t ws_size,
                              hipStream_t stream) {
  const float* x   = (const float*)d_in[0];
  const float* ew1 = (const float*)d_in[1];  const float* eb1 = (const float*)d_in[2];
  const float* ew2 = (const float*)d_in[3];  const float* eb2 = (const float*)d_in[4];
  const float* ew3 = (const float*)d_in[5];  const float* eb3 = (const float*)d_in[6];
  const float* emb = (const float*)d_in[7];
  const float* dw1 = (const float*)d_in[8];  const float* db1 = (const float*)d_in[9];
  const float* dw2 = (const float*)d_in[10]; const float* db2 = (const float*)d_in[11];
  const float* dw3 = (const float*)d_in[12]; const float* db3 = (const float*)d_in[13];
  float* out = (float*)d_out;

  // ws layout (bytes), total 134,219,776:
  //   h1  NHWC bf16 [32,128,128,64]  @ 0          (67108864)   -> reused as d2
  //   h2  NHWC bf16 [32, 64, 64,128] @ 67108864   (33554432)   -> reused as d1
  //   z   f32  [131072,32]           @ 100663296  (16777216)
  //   zq  f32  [131072,32]           @ 117440512  (16777216)
  //   part f32 [512]                 @ 134217728  (2048)
  //   wq2/wq3 overlaid in zq region (dead until vq); wq4/wq5 in z region
  //   (written after vq, when z is dead).
  uint8_t* w8 = (uint8_t*)d_ws;
  unsigned short* h1 = (unsigned short*)w8;
  unsigned short* h2 = (unsigned short*)(w8 + 67108864);
  float* z   = (float*)(w8 + 100663296);
  float* zq  = (float*)(w8 + 117440512);
  float* part = (float*)(w8 + 134217728);
  unsigned short* wq2 = (unsigned short*)(w8 + 117440512);            // 262144 B
  unsigned short* wq3 = (unsigned short*)(w8 + 117440512 + 262144);   // 73728 B
  unsigned short* wq4 = (unsigned short*)(w8 + 100663296);            // 73728 B
  unsigned short* wq5 = (unsigned short*)(w8 + 100663296 + 73728);    // 262144 B
  unsigned short* d1 = h2;
  unsigned short* d2 = h1;

  // encoder weight prep (into zq region, consumed before vq writes zq)
  prep2_k<<<dim3(512),256,0,stream>>>(ew2, wq2);
  prep3_k<<<dim3(144),256,0,stream>>>(ew3, wq3);
  // encoder
  conv1_k<<<dim3(1024),256,0,stream>>>(x, ew1, eb1, h1);
  mconv_k<64,128,128,2,4,16,1,1,false,true,false,false>
      <<<dim3(1024),256,0,stream>>>(h1, wq2, eb2, h2);
  mconv_k<128,32,64,1,3,9,1,1,false,true,false,true>
      <<<dim3(1024),256,0,stream>>>(h2, wq3, eb3, z);
  // VQ + loss
  vq_k<<<dim3(512),256,0,stream>>>(z, emb, zq, part);
  loss_k<<<dim3(1),512,0,stream>>>(part, out + 6291456);
  // decoder weight prep (into z region, dead after vq)
  prep4_k<<<dim3(144),256,0,stream>>>(dw1, wq4);
  prep5_k<<<dim3(512),256,0,stream>>>(dw2, wq5);
  // decoder
  mconv_k<32,128,64,1,3,9,1,1,false,true,true,false>
      <<<dim3(1024),256,0,stream>>>(zq, wq4, db1, d1);
  mconv_k<128,64,64,1,2,4,2,0,true,true,false,false>
      <<<dim3(1024,4),256,0,stream>>>(d1, wq5, db2, d2);
  convt3_k<<<dim3(4096),256,0,stream>>>(d2, dw3, db3, out);
}

// Round 5
// 638.684 us; speedup vs baseline: 1.1232x; 1.1232x over previous
//
#include <hip/hip_runtime.h>

// VQ-VAE forward, MI355X round 5: NHWC + MFMA implicit GEMM for the 4 big
// layers; conv1 (R3 version), convt3 (conflict-free LDS + 50% occupancy), VQ.
// fp32 I/O, bf16 intermediates.

typedef __attribute__((ext_vector_type(8))) short     short8;
typedef __attribute__((ext_vector_type(8))) __bf16    bf16x8;
typedef __attribute__((ext_vector_type(4))) float     f32x4;

#define BATCH 32

__device__ __forceinline__ float b2f(unsigned short b) {
  union { unsigned u; float f; } v; v.u = ((unsigned)b) << 16; return v.f;
}
__device__ __forceinline__ unsigned short f2b(float f) {  // round-to-nearest-even
  union { float f; unsigned u; } v; v.f = f;
  unsigned r = v.u + 0x7FFF + ((v.u >> 16) & 1);
  return (unsigned short)(r >> 16);
}

// ---------------- weight prep: reorganize to [tap][co][ci] bf16 -------------
__global__ __launch_bounds__(256) void prep2_k(const float* __restrict__ w,
                                               unsigned short* __restrict__ wq) {
  const int i = blockIdx.x*256 + threadIdx.x;                 // 131072 exact
  const int ci = i & 63, co = (i >> 6) & 127, t = i >> 13;
  wq[i] = f2b(w[(co*64 + ci)*16 + t]);                        // ew2 OIHW(128,64,4,4)
}
__global__ __launch_bounds__(256) void prep3_k(const float* __restrict__ w,
                                               unsigned short* __restrict__ wq) {
  const int i = blockIdx.x*256 + threadIdx.x;                 // 36864 exact
  const int ci = i & 127, co = (i >> 7) & 31, t = i >> 12;
  wq[i] = f2b(w[(co*128 + ci)*9 + t]);                        // ew3 OIHW(32,128,3,3)
}
__global__ __launch_bounds__(256) void prep4_k(const float* __restrict__ w,
                                               unsigned short* __restrict__ wq) {
  const int i = blockIdx.x*256 + threadIdx.x;                 // 36864 exact
  const int ci = i & 31, co = (i >> 5) & 127, t = i >> 12;
  wq[i] = f2b(w[(ci*128 + co)*9 + (8 - t)]);                  // dw1(32,128,3,3), flipped
}
__global__ __launch_bounds__(256) void prep5_k(const float* __restrict__ w,
                                               unsigned short* __restrict__ wq) {
  const int i = blockIdx.x*256 + threadIdx.x;                 // 131072 exact
  const int ci = i & 127, co = (i >> 7) & 63, t = (i >> 13) & 3, p = i >> 15;
  const int ky = 2 - 2*(t >> 1) + (1 - (p >> 1));
  const int kx = 2 - 2*(t & 1)  + (1 - (p & 1));
  wq[i] = f2b(w[(ci*64 + co)*16 + ky*4 + kx]);                // dw2(128,64,4,4)
}

// --------- MFMA implicit-GEMM conv: NHWC in -> NHWC out (64x64 spatial) -----
// M = 32*64*64 = 131072 output positions, block tile 128M x COUT, 4 waves.
// A (im2col) and B (weights [tap][co][ci]) staged per (tap, 32-ci chunk).
template<int CIN,int COUT,int HIN,int S,int KW,int NTAPS,int OSTRIDE,int P,
         bool PARITY,bool RELU,bool INF32,bool OUTF32>
__global__ __launch_bounds__(256) void mconv_k(const void* __restrict__ in_,
    const unsigned short* __restrict__ wq_, const float* __restrict__ bias,
    void* __restrict__ out_) {
  constexpr int NF  = COUT / 16;
  constexpr int NCH = CIN / 32;
  __shared__ short Al[128*40];      // 128 rows x 32 k, stride 40 (80B, 16B-mult)
  __shared__ short Bl[COUT*40];
  int py = 0, px = 0, PY = P, PX = P;
  const unsigned short* wq = wq_;
  if (PARITY) {
    py = blockIdx.y >> 1; px = blockIdx.y & 1;
    PY = 1 - py; PX = 1 - px;
    wq += blockIdx.y * (NTAPS*COUT*CIN);
  }
  const int m0 = blockIdx.x * 128;
  const int w  = threadIdx.x >> 6, l = threadIdx.x & 63;
  const int lm = l & 15, lk = l >> 4;
  f32x4 acc[2][NF];
  #pragma unroll
  for (int mi = 0; mi < 2; ++mi)
    #pragma unroll
    for (int ni = 0; ni < NF; ++ni) acc[mi][ni] = (f32x4)0.0f;

  for (int tap = 0; tap < NTAPS; ++tap) {
    const int ky = tap / KW, kx = tap % KW;
    for (int ch = 0; ch < NCH; ++ch) {
      const int c0 = ch * 32;
      __syncthreads();                       // prev iter frag reads done
      // ---- A stage: 128 rows x 64B, 4 lanes/row ----
      for (int s = threadIdx.x; s < 512; s += 256) {
        const int row = s >> 2, part = s & 3;
        const int m = m0 + row;
        const int n = m >> 12, oy = (m >> 6) & 63, ox = m & 63;
        const int iy = oy*S - PY + ky, ix = ox*S - PX + kx;
        short8 v = (short8)(short)0;
        if (iy >= 0 && iy < HIN && ix >= 0 && ix < HIN) {
          const int base = ((n*HIN + iy)*HIN + ix)*CIN + c0 + part*8;
          if (INF32) {
            const float* pf = (const float*)in_ + base;
            const f32x4 f0 = *(const f32x4*)pf;
            const f32x4 f1 = *(const f32x4*)(pf + 4);
            #pragma unroll
            for (int j = 0; j < 4; ++j) {
              v[j]     = (short)f2b(f0[j]);
              v[j + 4] = (short)f2b(f1[j]);
            }
          } else {
            v = *(const short8*)((const unsigned short*)in_ + base);
          }
        }
        *(short8*)&Al[row*40 + part*8] = v;
      }
      // ---- B stage: COUT rows x 64B ----
      for (int s = threadIdx.x; s < COUT*4; s += 256) {
        const int co = s >> 2, part = s & 3;
        *(short8*)&Bl[co*40 + part*8] =
            *(const short8*)(wq + (tap*COUT + co)*CIN + c0 + part*8);
      }
      __syncthreads();
      // ---- fragments + MFMA ----
      short8 av[2];
      #pragma unroll
      for (int mi = 0; mi < 2; ++mi)
        av[mi] = *(const short8*)&Al[(w*32 + mi*16 + lm)*40 + lk*8];
      #pragma unroll
      for (int ni = 0; ni < NF; ++ni) {
        const short8 bv = *(const short8*)&Bl[(ni*16 + lm)*40 + lk*8];
        #pragma unroll
        for (int mi = 0; mi < 2; ++mi)
          acc[mi][ni] = __builtin_amdgcn_mfma_f32_16x16x32_bf16(
              __builtin_bit_cast(bf16x8, av[mi]),
              __builtin_bit_cast(bf16x8, bv),
              acc[mi][ni], 0, 0, 0);
      }
    }
  }
  // ---- epilogue: C/D layout col=lane&15 (n), row=(lane>>4)*4+reg (m) ----
  #pragma unroll
  for (int ni = 0; ni < NF; ++ni) {
    const int co = ni*16 + lm;
    const float bv = bias[co];
    #pragma unroll
    for (int mi = 0; mi < 2; ++mi) {
      #pragma unroll
      for (int r = 0; r < 4; ++r) {
        const int ml = w*32 + mi*16 + lk*4 + r;
        const int m  = m0 + ml;
        float vv = acc[mi][ni][r] + bv;
        if (RELU) vv = fmaxf(vv, 0.f);
        int off;
        if (OSTRIDE == 1) {
          off = m*COUT + co;
        } else {
          const int n = m >> 12, oy = (m >> 6) & 63, ox = m & 63;
          off = ((n*128 + oy*2 + py)*128 + ox*2 + px)*COUT + co;
        }
        if (OUTF32) ((float*)out_)[off] = vv;
        else ((unsigned short*)out_)[off] = f2b(vv);
      }
    }
  }
}

// ---------------- conv1: x NCHW fp32 (3ch) -> h1 NHWC bf16 [32,128,128,64] --
// (R3 version — proven fast; R4's heavy-staging variant regressed.)
__global__ __launch_bounds__(256) void conv1_k(const float* __restrict__ x,
    const float* __restrict__ w, const float* __restrict__ bias,
    unsigned short* __restrict__ out) {
  __shared__ float wl[64*48];
  __shared__ float bl[64];
  for (int t = threadIdx.x; t < 3072; t += 256) wl[t] = w[t];
  if (threadIdx.x < 64) bl[threadIdx.x] = bias[threadIdx.x];
  __syncthreads();
  const int n  = blockIdx.x >> 6, oy = (blockIdx.x & 63)*2 + (threadIdx.x >> 7);
  const int ox = threadIdx.x & 127;
  float xin[48];
  #pragma unroll
  for (int ci = 0; ci < 3; ++ci)
    #pragma unroll
    for (int ky = 0; ky < 4; ++ky) {
      const int iy = oy*2 - 1 + ky;
      #pragma unroll
      for (int kx = 0; kx < 4; ++kx) {
        const int ix = ox*2 - 1 + kx;
        float v = 0.f;
        if (iy >= 0 && iy < 256 && ix >= 0 && ix < 256)
          v = x[((n*3 + ci)*256 + iy)*256 + ix];
        xin[ci*16 + ky*4 + kx] = v;
      }
    }
  const int ob = ((n*128 + oy)*128 + ox)*64;
  #pragma unroll
  for (int cb = 0; cb < 8; ++cb) {
    short8 sv;
    #pragma unroll
    for (int j = 0; j < 8; ++j) {
      const int co = cb*8 + j;
      float a = bl[co];
      #pragma unroll
      for (int q = 0; q < 12; ++q) {
        const f32x4 wv = *(const f32x4*)&wl[co*48 + q*4];
        a = fmaf(xin[q*4+0], wv[0], a);
        a = fmaf(xin[q*4+1], wv[1], a);
        a = fmaf(xin[q*4+2], wv[2], a);
        a = fmaf(xin[q*4+3], wv[3], a);
      }
      sv[j] = (short)f2b(fmaxf(a, 0.f));
    }
    *(short8*)&out[ob + cb*8] = sv;
  }
}

// ------- VQ: z fp32 [131072,32] -> zq fp32 [131072,32] + loss partials ------
// embed chunk transposed [c][j] in LDS; 4-code vector dot accumulation.
__global__ __launch_bounds__(256) void vq_k(const float* __restrict__ z,
    const float* __restrict__ embed, float* __restrict__ zq,
    float* __restrict__ partial) {
  __shared__ float EL[32*256];    // [c][j] transposed chunk (32 KB)
  __shared__ float en[256];
  __shared__ float red[256];
  const int p = blockIdx.x*256 + threadIdx.x;   // 0..131071
  float zf[32];
  #pragma unroll
  for (int c4 = 0; c4 < 8; ++c4) {
    const f32x4 v = *(const f32x4*)&z[(long)p*32 + c4*4];
    #pragma unroll
    for (int e = 0; e < 4; ++e) zf[c4*4 + e] = v[e];
  }
  float best = 1e30f; int bi = 0;
  for (int chunk = 0; chunk < 2; ++chunk) {
    __syncthreads();
    for (int i = threadIdx.x; i < 8192; i += 256) {
      const int c = i >> 8, j = i & 255;
      EL[c*256 + j] = embed[(chunk*256 + j)*32 + c];
    }
    __syncthreads();
    {
      float s = 0.f;
      #pragma unroll
      for (int c = 0; c < 32; ++c)
        s = fmaf(EL[c*256 + threadIdx.x], EL[c*256 + threadIdx.x], s);
      en[threadIdx.x] = s;
    }
    __syncthreads();
    for (int j8 = 0; j8 < 256; j8 += 8) {
      f32x4 dA = (f32x4)0.0f, dB = (f32x4)0.0f;
      #pragma unroll
      for (int c = 0; c < 32; ++c) {
        const f32x4 eA = *(const f32x4*)&EL[c*256 + j8];
        const f32x4 eB = *(const f32x4*)&EL[c*256 + j8 + 4];
        dA += eA * zf[c];
        dB += eB * zf[c];
      }
      #pragma unroll
      for (int k = 0; k < 4; ++k) {
        const float d = en[j8 + k] - 2.f*dA[k];
        if (d < best) { best = d; bi = chunk*256 + j8 + k; }
      }
      #pragma unroll
      for (int k = 0; k < 4; ++k) {
        const float d = en[j8 + 4 + k] - 2.f*dB[k];
        if (d < best) { best = d; bi = chunk*256 + j8 + 4 + k; }
      }
    }
  }
  float se = 0.f;
  #pragma unroll
  for (int c = 0; c < 32; ++c) {
    const float e = embed[bi*32 + c];          // exact fp32 codeword
    zq[(long)p*32 + c] = e;
    const float df = e - zf[c];
    se = fmaf(df, df, se);
  }
  red[threadIdx.x] = se; __syncthreads();
  for (int s = 128; s > 0; s >>= 1) {
    if (threadIdx.x < s) red[threadIdx.x] += red[threadIdx.x + s];
    __syncthreads();
  }
  if (threadIdx.x == 0) partial[blockIdx.x] = red[0];
}

__global__ __launch_bounds__(512) void loss_k(const float* __restrict__ part,
                                              float* __restrict__ out) {
  __shared__ float red[512];
  const int t = threadIdx.x;
  red[t] = part[t]; __syncthreads();
  for (int s = 256; s > 0; s >>= 1) {
    if (t < s) red[t] += red[t + s];
    __syncthreads();
  }
  if (t == 0) out[0] = red[0] * (1.25f / (131072.f * 32.f));
}

// -------- convt3: d2 NHWC bf16 [32,128,128,64] -> x_recon NCHW fp32 ---------
// block = (n, input-row q, x-half h): output rows 2q,2q+1, cols [h*128,h*128+128).
// IL chunk-major [r][c8][ixl]: inner-loop lane stride = 16B -> conflict-free.
// 37.6 KB LDS -> 4 blocks/CU. Wave = (py,px) uniform -> weight reads broadcast.
__global__ __launch_bounds__(256) void convt3_k(const unsigned short* __restrict__ in,
    const float* __restrict__ w, const float* __restrict__ bias,
    float* __restrict__ out) {
  __shared__ short8 IL[3*8*66];      // [(r*8+c8)*66 + ixl], 25344 B
  __shared__ float  wt[16*192];      // [tap][co][ci] fp32, 12288 B
  const int h = blockIdx.x & 1, q = (blockIdx.x >> 1) & 127, n = blockIdx.x >> 8;
  for (int i = threadIdx.x; i < 3072; i += 256) {
    const int tap = i / 192, rem = i % 192, co = rem >> 6, ci = rem & 63;
    wt[i] = w[(ci*3 + co)*16 + tap];                // dw3 (64,3,4,4)
  }
  // stage 3 input rows x 66 cols (halo +-1), c8 fastest -> coalesced global
  for (int i = threadIdx.x; i < 1584; i += 256) {   // 3*66*8
    const int c8 = i & 7, t = i >> 3, ixl = t % 66, r = t / 66;
    const int iy = q - 1 + r, ix = h*64 - 1 + ixl;
    short8 v = (short8)(short)0;
    if (iy >= 0 && iy < 128 && ix >= 0 && ix < 128)
      v = *(const short8*)(in + (((long)(n*128 + iy)*128 + ix)*64 + c8*8));
    IL[(r*8 + c8)*66 + ixl] = v;
  }
  __syncthreads();
  // wave mapping: px = bit7, py = bit6 (both wave-uniform), xq = lane
  const int px = threadIdx.x >> 7, py = (threadIdx.x >> 6) & 1;
  const int xq = threadIdx.x & 63;
  float acc[3];
  #pragma unroll
  for (int co = 0; co < 3; ++co) acc[co] = bias[co];
  #pragma unroll
  for (int c8 = 0; c8 < 8; ++c8) {
    short8 v[2][2];                                  // [a][b]
    #pragma unroll
    for (int a = 0; a < 2; ++a)
      #pragma unroll
      for (int b = 0; b < 2; ++b)
        v[a][b] = IL[((py + a)*8 + c8)*66 + xq + px + b];
    #pragma unroll
    for (int a = 0; a < 2; ++a) {
      const int ky = 2 - 2*a + (1 - py);
      #pragma unroll
      for (int b = 0; b < 2; ++b) {
        const int kx = 2 - 2*b + (1 - px);
        const int tap = ky*4 + kx;
        float vf[8];
        #pragma unroll
        for (int j = 0; j < 8; ++j) vf[j] = b2f((unsigned short)v[a][b][j]);
        #pragma unroll
        for (int co = 0; co < 3; ++co) {
          const f32x4 w0 = *(const f32x4*)&wt[tap*192 + co*64 + c8*8];
          const f32x4 w1 = *(const f32x4*)&wt[tap*192 + co*64 + c8*8 + 4];
          float a0 = acc[co];
          a0 = fmaf(vf[0], w0[0], a0);
          a0 = fmaf(vf[1], w0[1], a0);
          a0 = fmaf(vf[2], w0[2], a0);
          a0 = fmaf(vf[3], w0[3], a0);
          a0 = fmaf(vf[4], w1[0], a0);
          a0 = fmaf(vf[5], w1[1], a0);
          a0 = fmaf(vf[6], w1[2], a0);
          a0 = fmaf(vf[7], w1[3], a0);
          acc[co] = a0;
        }
      }
    }
  }
  const int oy = 2*q + py, ox = h*128 + 2*xq + px;
  #pragma unroll
  for (int co = 0; co < 3; ++co)
    out[((long)(n*3 + co))*65536 + oy*256 + ox] = acc[co];
}

extern "C" void kernel_launch(void* const* d_in, const int* in_sizes, int n_in,
                              void* d_out, int out_size, void* d_ws, size_t ws_size,
                              hipStream_t stream) {
  const float* x   = (const float*)d_in[0];
  const float* ew1 = (const float*)d_in[1];  const float* eb1 = (const float*)d_in[2];
  const float* ew2 = (const float*)d_in[3];  const float* eb2 = (const float*)d_in[4];
  const float* ew3 = (const float*)d_in[5];  const float* eb3 = (const float*)d_in[6];
  const float* emb = (const float*)d_in[7];
  const float* dw1 = (const float*)d_in[8];  const float* db1 = (const float*)d_in[9];
  const float* dw2 = (const float*)d_in[10]; const float* db2 = (const float*)d_in[11];
  const float* dw3 = (const float*)d_in[12]; const float* db3 = (const float*)d_in[13];
  float* out = (float*)d_out;

  // ws layout (bytes), total 134,219,776:
  //   h1  NHWC bf16 [32,128,128,64]  @ 0          (67108864)   -> reused as d2
  //   h2  NHWC bf16 [32, 64, 64,128] @ 67108864   (33554432)   -> reused as d1
  //   z   f32  [131072,32]           @ 100663296  (16777216)
  //   zq  f32  [131072,32]           @ 117440512  (16777216)
  //   part f32 [512]                 @ 134217728  (2048)
  //   wq2/wq3 overlaid in zq region (dead until vq); wq4/wq5 in z region
  //   (written after vq, when z is dead).
  uint8_t* w8 = (uint8_t*)d_ws;
  unsigned short* h1 = (unsigned short*)w8;
  unsigned short* h2 = (unsigned short*)(w8 + 67108864);
  float* z   = (float*)(w8 + 100663296);
  float* zq  = (float*)(w8 + 117440512);
  float* part = (float*)(w8 + 134217728);
  unsigned short* wq2 = (unsigned short*)(w8 + 117440512);            // 262144 B
  unsigned short* wq3 = (unsigned short*)(w8 + 117440512 + 262144);   // 73728 B
  unsigned short* wq4 = (unsigned short*)(w8 + 100663296);            // 73728 B
  unsigned short* wq5 = (unsigned short*)(w8 + 100663296 + 73728);    // 262144 B
  unsigned short* d1 = h2;
  unsigned short* d2 = h1;

  // encoder weight prep (into zq region, consumed before vq writes zq)
  prep2_k<<<dim3(512),256,0,stream>>>(ew2, wq2);
  prep3_k<<<dim3(144),256,0,stream>>>(ew3, wq3);
  // encoder
  conv1_k<<<dim3(2048),256,0,stream>>>(x, ew1, eb1, h1);
  mconv_k<64,128,128,2,4,16,1,1,false,true,false,false>
      <<<dim3(1024),256,0,stream>>>(h1, wq2, eb2, h2);
  mconv_k<128,32,64,1,3,9,1,1,false,true,false,true>
      <<<dim3(1024),256,0,stream>>>(h2, wq3, eb3, z);
  // VQ + loss
  vq_k<<<dim3(512),256,0,stream>>>(z, emb, zq, part);
  loss_k<<<dim3(1),512,0,stream>>>(part, out + 6291456);
  // decoder weight prep (into z region, dead after vq)
  prep4_k<<<dim3(144),256,0,stream>>>(dw1, wq4);
  prep5_k<<<dim3(512),256,0,stream>>>(dw2, wq5);
  // decoder
  mconv_k<32,128,64,1,3,9,1,1,false,true,true,false>
      <<<dim3(1024),256,0,stream>>>(zq, wq4, db1, d1);
  mconv_k<128,64,64,1,2,4,2,0,true,true,false,false>
      <<<dim3(1024,4),256,0,stream>>>(d1, wq5, db2, d2);
  convt3_k<<<dim3(8192),256,0,stream>>>(d2, dw3, db3, out);
}